// Round 6
// baseline (782.778 us; speedup 1.0000x reference)
//
#include <hip/hip_runtime.h>

#define NN 100000   // nodes
#define NE 1600000  // edges
#define NR 8        // relations
#define DD 128      // feature dim
#define NKEY (NN * NR)               // 800000 (dst,rel) keys
#define NBLK ((NKEY + 1023) / 1024)  // 782 scan blocks
#define RSTRIDE 580                  // dwords per node row in sAgg (576 data + 4 pad)
#define CASTN (NN * DD / 4)          // 3200000
#define WTN (2 * 9 * 16384)          // 294912

typedef __attribute__((ext_vector_type(8))) short short8;
typedef __attribute__((ext_vector_type(4))) float f32x4;

__device__ __forceinline__ unsigned short f2bf(float f) {
  union { float f; unsigned int i; } c; c.f = f;
  unsigned int u = c.i;
  return (unsigned short)((u + 0x7FFFu + ((u >> 16) & 1u)) >> 16);  // RNE
}

// ---- preprocessing ----------------------------------------------------------

// merged: x->bf16 cast | weight transpose+cast | cnt zero-init
__global__ __launch_bounds__(256) void k_prep(
    const float* __restrict__ x,
    const float* __restrict__ W1, const float* __restrict__ root1,
    const float* __restrict__ W2, const float* __restrict__ root2,
    unsigned short* __restrict__ xb, unsigned short* __restrict__ wbf,
    int* __restrict__ cnt) {
  int i = blockIdx.x * 256 + threadIdx.x;
  if (i < CASTN) {
    float4 f = ((const float4*)x)[i];
    ushort4 u;
    u.x = f2bf(f.x); u.y = f2bf(f.y); u.z = f2bf(f.z); u.w = f2bf(f.w);
    ((ushort4*)xb)[i] = u;
  } else if (i < CASTN + WTN) {
    int idx = i - CASTN;                 // wbf[layer][rb][n][k] = W[rb][k][n]
    int layer = idx / (9 * 16384);
    int rem = idx % (9 * 16384);
    int r = rem / 16384;
    int nk = rem % 16384;
    int n = nk >> 7, k = nk & 127;
    float v;
    if (r < 8) v = (layer ? W2 : W1)[r * 16384 + k * 128 + n];
    else       v = (layer ? root2 : root1)[k * 128 + n];
    wbf[idx] = f2bf(v);
  } else if (i < CASTN + WTN + NKEY) {
    cnt[i - CASTN - WTN] = 0;
  }
}

__global__ __launch_bounds__(256) void k_count(
    const int* __restrict__ ei, const int* __restrict__ et, int* __restrict__ cnt) {
  int e = blockIdx.x * 256 + threadIdx.x;
  if (e < NE) {
    int dst = ei[NE + e];
    int r = et[e];
    atomicAdd(&cnt[dst * NR + r], 1);
  }
}

// hierarchical exclusive scan over NKEY elements
__global__ __launch_bounds__(1024) void k_scan1(
    const int* __restrict__ cnt, int* __restrict__ offs, int* __restrict__ bsum) {
  __shared__ int sd[1024];
  int t = threadIdx.x, b = blockIdx.x;
  int i = b * 1024 + t;
  int v = (i < NKEY) ? cnt[i] : 0;
  sd[t] = v;
  __syncthreads();
  for (int o = 1; o < 1024; o <<= 1) {
    int tv = (t >= o) ? sd[t - o] : 0;
    __syncthreads();
    sd[t] += tv;
    __syncthreads();
  }
  if (i < NKEY) offs[i] = sd[t] - v;               // block-local exclusive
  if (t == 1023) bsum[b] = sd[t];
}

__global__ __launch_bounds__(1024) void k_scan2(int* __restrict__ bsum) {
  __shared__ int sd[1024];
  int t = threadIdx.x;
  int v = (t < NBLK) ? bsum[t] : 0;
  sd[t] = v;
  __syncthreads();
  for (int o = 1; o < 1024; o <<= 1) {
    int tv = (t >= o) ? sd[t - o] : 0;
    __syncthreads();
    sd[t] += tv;
    __syncthreads();
  }
  if (t < NBLK) bsum[t] = sd[t] - v;               // exclusive block bases
}

__global__ __launch_bounds__(256) void k_scan3(
    int* __restrict__ offs, const int* __restrict__ bsum) {
  int i = blockIdx.x * 256 + threadIdx.x;
  if (i < NKEY) offs[i] += bsum[i >> 10];
  if (i == 0) offs[NKEY] = NE;
}

// scatter edges as src | keyid<<17 (keyid = block-local (dst&31)*8+rel);
// reuses cnt as the fill counter (atomicSub)
__global__ __launch_bounds__(256) void k_csr(
    const int* __restrict__ ei, const int* __restrict__ et,
    const int* __restrict__ offs, int* __restrict__ cnt,
    unsigned int* __restrict__ csr) {
  int e = blockIdx.x * 256 + threadIdx.x;
  if (e < NE) {
    int src = ei[e];
    int dst = ei[NE + e];
    int r = et[e];
    int key = dst * NR + r;
    int old = atomicSub(&cnt[key], 1);
    unsigned rec = (unsigned)src | ((unsigned)(((dst & 31) << 3) | r) << 17);
    csr[offs[key] + old - 1] = rec;
  }
}

// ---- fused per-layer kernel -------------------------------------------------
// Block (256 thr, 4 waves) owns 32 dst nodes = 256 keys. Wave w owns keys
// [64w, 64w+64) = one contiguous csr range. Scalarized edge stream: keyid
// embedded in the csr record, readlane -> SGPR -> SALU key logic; depth-2x16
// software-pipelined gathers in 4 rotating unrolled register buffers; one
// ds_write per key (no atomics). MFMA: M=32, B-frags reused over 2 row-tiles.

#define FLUSH() do {                                                          \
    float nm_ = __builtin_amdgcn_rcpf((float)ec);                             \
    union { float f; unsigned i; } ux_, uy_;                                  \
    ux_.f = sx * nm_; uy_.f = sy * nm_;                                       \
    unsigned pk_ = ((ux_.i + 0x8000u) >> 16) | ((uy_.i + 0x8000u) & 0xFFFF0000u); \
    sAgg32[(cur >> 3) * RSTRIDE + ((cur & 7) << 6) + lane] = pk_;             \
  } while (0)

#define ISSUE(PV, SLOT, IDX0)                                                 \
  _Pragma("unroll")                                                           \
  for (int j = 0; j < 16; j++) {                                              \
    unsigned rec_ = (unsigned)__builtin_amdgcn_readlane((int)(PV), (IDX0) + j); \
    buf[SLOT][j] = *(const unsigned int*)(xb + (size_t)(rec_ & 0x1FFFFu) * DD + 2 * lane); \
  }

#define CONSUME(SLOT, B, WIN)                                                 \
  _Pragma("unroll")                                                           \
  for (int j = 0; j < 16; j++) {                                              \
    int p_ = (WIN) + (B) * 16 + j;                                            \
    if (p_ >= p0 && p_ < p1) {                                                \
      int kk = (int)(((unsigned)__builtin_amdgcn_readlane((int)pv, (B) * 16 + j)) >> 17); \
      if (kk != cur) {                                                        \
        if (cur >= 0) FLUSH();                                                \
        int zs = (cur < 0) ? kbase : cur + 1;                                 \
        for (int z = zs; z < kk; z++)                                         \
          sAgg32[(z >> 3) * RSTRIDE + ((z & 7) << 6) + lane] = 0u;            \
        cur = kk; sx = 0.f; sy = 0.f; ec = 0;                                 \
      }                                                                       \
      unsigned u_ = buf[SLOT][j];                                             \
      union { unsigned i; float f; } lo_, hi_;                                \
      lo_.i = u_ << 16; hi_.i = u_ & 0xFFFF0000u;                             \
      sx += lo_.f; sy += hi_.f; ec++;                                         \
    }                                                                         \
  }

template <int RELU, int OUTBF>
__global__ __launch_bounds__(256, 2) void k_fused(
    const unsigned short* __restrict__ xb,   // [N][128] bf16
    const unsigned short* __restrict__ wl,   // [9][128][128] n-major bf16
    const int* __restrict__ offs, const unsigned int* __restrict__ csr,
    const float* __restrict__ bias, void* __restrict__ outp) {
  __shared__ unsigned int sAgg32[32 * RSTRIDE];    // 74240 B -> 2 blocks/CU
  const unsigned short* sAggH = (const unsigned short*)sAgg32;

  const int tid = threadIdx.x;
  const int w = tid >> 6;
  const int lane = tid & 63;
  const int m = lane & 15, q = lane >> 4;
  const int n0 = blockIdx.x * 32;
  const int kbase = 64 * w;                        // block-local key base
  const int K0 = n0 * NR + kbase;

  // root rows (rel-slot 8) for this wave's 8 nodes
#pragma unroll
  for (int i = 0; i < 8; i++) {
    int node = 8 * w + i;
    sAgg32[node * RSTRIDE + 512 + lane] =
        *(const unsigned int*)(xb + (size_t)(n0 + node) * DD + 2 * lane);
  }

  const int p0 = offs[K0];
  const int p1 = offs[K0 + 64];

  int cur = -1, ec = 0;
  float sx = 0.f, sy = 0.f;
  unsigned int buf[4][16];

  const int win0 = p0 & ~63;
  unsigned int pv = csr[win0 + lane];              // csr padded +128 ints
  ISSUE(pv, 0, 0)
  ISSUE(pv, 1, 16)
  for (int win = win0; win < p1; win += 64) {
    unsigned int pvn = csr[win + 64 + lane];
    ISSUE(pv, 2, 32)
    CONSUME(0, 0, win)
    ISSUE(pv, 3, 48)
    CONSUME(1, 1, win)
    ISSUE(pvn, 0, 0)
    CONSUME(2, 2, win)
    ISSUE(pvn, 1, 16)
    CONSUME(3, 3, win)
    pv = pvn;
  }
  if (cur >= 0) FLUSH();
  {
    int zs = (cur < 0) ? kbase : cur + 1;
    for (int z = zs; z < kbase + 64; z++)
      sAgg32[(z >> 3) * RSTRIDE + ((z & 7) << 6) + lane] = 0u;
  }
  __syncthreads();

  // ---- MFMA: wave w -> col-tiles {2w, 2w+1}, row-tiles {0,1}, 9 matrices ----
  f32x4 acc[2][2];
#pragma unroll
  for (int rt = 0; rt < 2; rt++)
#pragma unroll
    for (int ct = 0; ct < 2; ct++) acc[rt][ct] = (f32x4){0.f, 0.f, 0.f, 0.f};
  const int nt0 = 2 * w, nt1 = 2 * w + 1;
  for (int mat = 0; mat < 9; mat++) {
    const unsigned short* wr = wl + mat * DD * DD;
#pragma unroll
    for (int ks = 0; ks < 4; ks++) {
      short8 b0 = *(const short8*)(wr + (nt0 * 16 + m) * DD + ks * 32 + q * 8);
      short8 b1 = *(const short8*)(wr + (nt1 * 16 + m) * DD + ks * 32 + q * 8);
      short8 a0 = *(const short8*)(sAggH + (m) * (2 * RSTRIDE) + mat * 128 + ks * 32 + q * 8);
      short8 a1 = *(const short8*)(sAggH + (16 + m) * (2 * RSTRIDE) + mat * 128 + ks * 32 + q * 8);
      acc[0][0] = __builtin_amdgcn_mfma_f32_16x16x32_bf16(a0, b0, acc[0][0], 0, 0, 0);
      acc[0][1] = __builtin_amdgcn_mfma_f32_16x16x32_bf16(a0, b1, acc[0][1], 0, 0, 0);
      acc[1][0] = __builtin_amdgcn_mfma_f32_16x16x32_bf16(a1, b0, acc[1][0], 0, 0, 0);
      acc[1][1] = __builtin_amdgcn_mfma_f32_16x16x32_bf16(a1, b1, acc[1][1], 0, 0, 0);
    }
  }

  // epilogue: C/D row = q*4+i, col = nt*16+m
#pragma unroll
  for (int ct = 0; ct < 2; ct++) {
    int col = (2 * w + ct) * 16 + m;
    float bv = bias[col];
#pragma unroll
    for (int rt = 0; rt < 2; rt++)
#pragma unroll
      for (int i = 0; i < 4; i++) {
        int row = n0 + rt * 16 + q * 4 + i;
        float v = acc[rt][ct][i] + bv;
        if (RELU) v = fmaxf(v, 0.f);
        if (OUTBF) ((unsigned short*)outp)[(size_t)row * DD + col] = f2bf(v);
        else       ((float*)outp)[(size_t)row * DD + col] = v;
      }
  }
}

// ---- launch -----------------------------------------------------------------

extern "C" void kernel_launch(void* const* d_in, const int* in_sizes, int n_in,
                              void* d_out, int out_size, void* d_ws, size_t ws_size,
                              hipStream_t stream) {
  const float* x     = (const float*)d_in[0];
  const int*   ei    = (const int*)d_in[1];
  const int*   et    = (const int*)d_in[2];
  const float* W1    = (const float*)d_in[3];
  const float* root1 = (const float*)d_in[4];
  const float* b1    = (const float*)d_in[5];
  const float* W2    = (const float*)d_in[6];
  const float* root2 = (const float*)d_in[7];
  const float* b2    = (const float*)d_in[8];
  float* out = (float*)d_out;

  char* p = (char*)d_ws;
  unsigned short* xb1 = (unsigned short*)p; p += (size_t)NN * DD * 2;   // 25.6 MB
  unsigned short* xb2 = (unsigned short*)p; p += (size_t)NN * DD * 2;   // 25.6 MB
  unsigned short* wbf = (unsigned short*)p; p += (size_t)WTN * 2;       // 0.6 MB
  int* cnt  = (int*)p; p += (size_t)NKEY * 4;                           // 3.2 MB
  int* offs = (int*)p; p += (size_t)(NKEY + 16) * 4;                    // 3.2 MB
  int* bsum = (int*)p; p += (size_t)1024 * 4;
  unsigned int* csr = (unsigned int*)p; p += (size_t)(NE + 128) * 4;    // 6.4 MB (+pad)
  // total ~= 64.6 MB

  k_prep<<<(CASTN + WTN + NKEY + 255) / 256, 256, 0, stream>>>(
      x, W1, root1, W2, root2, xb1, wbf, cnt);
  k_count<<<(NE + 255) / 256, 256, 0, stream>>>(ei, et, cnt);
  k_scan1<<<NBLK, 1024, 0, stream>>>(cnt, offs, bsum);
  k_scan2<<<1, 1024, 0, stream>>>(bsum);
  k_scan3<<<(NKEY + 255) / 256, 256, 0, stream>>>(offs, bsum);
  k_csr<<<(NE + 255) / 256, 256, 0, stream>>>(ei, et, offs, cnt, csr);

  dim3 fgrid(NN / 32);   // 3125
  k_fused<1, 1><<<fgrid, 256, 0, stream>>>(xb1, wbf, offs, csr, b1, (void*)xb2);
  k_fused<0, 0><<<fgrid, 256, 0, stream>>>(xb2, wbf + 9 * DD * DD, offs, csr, b2, (void*)out);
}